// Round 3
// baseline (528.221 us; speedup 1.0000x reference)
//
#include <hip/hip_runtime.h>

typedef __attribute__((ext_vector_type(8))) short bf16x8;
typedef __attribute__((ext_vector_type(4))) float f32x4;
typedef unsigned short u16;
typedef unsigned int u32;

#define T_SEQ 2048
#define C_DIM 1024
#define NH 16
#define HD 64
#define BATCH 2

__device__ __forceinline__ u16 f2bf(float f) {
    union { float f; u32 u; } v; v.f = f;
    u32 u = v.u;
    u32 r = (u + 0x7FFFu + ((u >> 16) & 1u)) >> 16;
    return (u16)r;
}

__device__ __forceinline__ float fexp2(float x) { return __builtin_amdgcn_exp2f(x); }

// ---------------------------------------------------------------------------
// Transpose 4 weight matrices [C,C] f32 -> [C,C] bf16 (WT[n][k] = W[k][n])
// ---------------------------------------------------------------------------
__global__ __launch_bounds__(256) void transpose_to_bf16(
    const float* __restrict__ W0, const float* __restrict__ W1,
    const float* __restrict__ W2, const float* __restrict__ W3,
    u16* __restrict__ O0, u16* __restrict__ O1,
    u16* __restrict__ O2, u16* __restrict__ O3)
{
    __shared__ float tile[32][33];
    const float* W = blockIdx.z == 0 ? W0 : blockIdx.z == 1 ? W1 : blockIdx.z == 2 ? W2 : W3;
    u16* O = blockIdx.z == 0 ? O0 : blockIdx.z == 1 ? O1 : blockIdx.z == 2 ? O2 : O3;
    const int tx = threadIdx.x, ty = threadIdx.y;
    const int bx = blockIdx.x * 32, by = blockIdx.y * 32;
#pragma unroll
    for (int i = 0; i < 4; ++i)
        tile[ty + i * 8][tx] = W[(size_t)(by + ty + i * 8) * C_DIM + bx + tx];
    __syncthreads();
#pragma unroll
    for (int i = 0; i < 4; ++i)
        O[(size_t)(bx + ty + i * 8) * C_DIM + by + tx] = f2bf(tile[tx][ty + i * 8]);
}

// ---------------------------------------------------------------------------
// GEMM: Y[M,N] = X[M,K] @ W[K,N] + bias, with WT[N,K] (pre-transposed bf16).
// OMODE: 0 = bf16 row-major, 1 = f32 row-major,
//        2 = bf16 transposed per-head: Y[b][h][d][t]  (for V^T)
// ---------------------------------------------------------------------------
template<bool XF32, int OMODE>
__global__ __launch_bounds__(256) void gemm_bt(
    const void* __restrict__ Xv, const u16* __restrict__ WT,
    const float* __restrict__ bias, void* __restrict__ Yv,
    int M, int N, int K)
{
    __shared__ u16 As[128 * 32];
    __shared__ u16 Bs[128 * 32];
    const int tid = threadIdx.x;
    const int w = tid >> 6, l = tid & 63;
    const int lr = l & 15, lg = l >> 4;
    const int m0 = blockIdx.y * 128, n0 = blockIdx.x * 128;
    const int wr = (w >> 1) * 64, wc = (w & 1) * 64;
    f32x4 acc[4][4] = {};

    for (int k0 = 0; k0 < K; k0 += 32) {
        __syncthreads();
#pragma unroll
        for (int r = 0; r < 2; ++r) {
            const int idx = r * 256 + tid;      // 0..511
            const int row = idx >> 2, cg = idx & 3;
            if (XF32) {
                const float* g = (const float*)Xv + (size_t)(m0 + row) * K + k0 + cg * 8;
                float4 a0 = *(const float4*)g;
                float4 a1 = *(const float4*)(g + 4);
                union { u16 h[8]; uint4 q; } pk;
                pk.h[0] = f2bf(a0.x); pk.h[1] = f2bf(a0.y);
                pk.h[2] = f2bf(a0.z); pk.h[3] = f2bf(a0.w);
                pk.h[4] = f2bf(a1.x); pk.h[5] = f2bf(a1.y);
                pk.h[6] = f2bf(a1.z); pk.h[7] = f2bf(a1.w);
                *(uint4*)&As[row * 32 + cg * 8] = pk.q;
            } else {
                const u16* g = (const u16*)Xv + (size_t)(m0 + row) * K + k0 + cg * 8;
                *(uint4*)&As[row * 32 + cg * 8] = *(const uint4*)g;
            }
            const u16* gb = WT + (size_t)(n0 + row) * K + k0 + cg * 8;
            *(uint4*)&Bs[row * 32 + cg * 8] = *(const uint4*)gb;
        }
        __syncthreads();
        bf16x8 af[4], bfr[4];
#pragma unroll
        for (int i = 0; i < 4; ++i)
            af[i] = *(const bf16x8*)&As[(wr + i * 16 + lr) * 32 + lg * 8];
#pragma unroll
        for (int j = 0; j < 4; ++j)
            bfr[j] = *(const bf16x8*)&Bs[(wc + j * 16 + lr) * 32 + lg * 8];
#pragma unroll
        for (int i = 0; i < 4; ++i)
#pragma unroll
            for (int j = 0; j < 4; ++j)
                acc[i][j] = __builtin_amdgcn_mfma_f32_16x16x32_bf16(af[i], bfr[j], acc[i][j], 0, 0, 0);
    }

#pragma unroll
    for (int i = 0; i < 4; ++i) {
        const int rowb = m0 + wr + i * 16 + lg * 4;
#pragma unroll
        for (int j = 0; j < 4; ++j) {
            const int col = n0 + wc + j * 16 + lr;
            const float bv = bias[col];
            if (OMODE == 2) {
                union { u16 h[4]; uint2 q; } pk;
#pragma unroll
                for (int r = 0; r < 4; ++r) pk.h[r] = f2bf(acc[i][j][r] + bv);
                const int bb = rowb >> 11, tt = rowb & 2047;
                const int hh = col >> 6, dd = col & 63;
                u16* dst = (u16*)Yv + ((size_t)((bb * NH + hh) * HD + dd)) * T_SEQ + tt;
                *(uint2*)dst = pk.q;
            } else {
#pragma unroll
                for (int r = 0; r < 4; ++r) {
                    const float v = acc[i][j][r] + bv;
                    if (OMODE == 1)
                        ((float*)Yv)[(size_t)(rowb + r) * N + col] = v;
                    else
                        ((u16*)Yv)[(size_t)(rowb + r) * N + col] = f2bf(v);
                }
            }
        }
    }
}

// ---------------------------------------------------------------------------
// Causal attention, 2-pass flash, swapped QK^T (S^T = K·Q^T).
// ONE WAVE PER BLOCK (64 thr), 16 q-rows per wave; 4096 blocks for TLP.
// Heavy strips (large q0) launched first. K software-pipelined; V loads
// hoisted; zero-fill is a tight trailing store loop.
// ---------------------------------------------------------------------------
__global__ __launch_bounds__(64) void attn_kernel(
    const u16* __restrict__ qp, const u16* __restrict__ kp,
    const u16* __restrict__ vt, u16* __restrict__ ctx,
    float* __restrict__ attn)
{
    __shared__ u16 plds[16][40];   // P tile [q][kv], stride 40 u16
    const int l = threadIdx.x & 63;
    const int lr = l & 15, lg = l >> 4;
    const int b = blockIdx.z, h = blockIdx.y;
    const int strip = (gridDim.x - 1) - blockIdx.x;   // heavy-first
    const int q0 = strip * 16;

    const size_t bh_off = (size_t)b * T_SEQ * C_DIM + h * HD;
    const u16* qb = qp + bh_off;
    const u16* kb = kp + bh_off;
    const u16* vtb = vt + ((size_t)(b * NH + h) * HD) * T_SEQ;
    float* ab = attn + (size_t)(b * NH + h) * T_SEQ * T_SEQ;

    const float SC = 0.125f * 1.44269504088896f;   // 1/sqrt(64) * log2(e)

    const bf16x8 aq0 = *(const bf16x8*)(qb + (size_t)(q0 + lr) * C_DIM + lg * 8);
    const bf16x8 aq1 = *(const bf16x8*)(qb + (size_t)(q0 + lr) * C_DIM + 32 + lg * 8);

    const int qrow = q0 + lr;
    const int kv_end = q0 + 16;     // exclusive kv bound

    bf16x8 kc[4], kn[4];
    auto loadK = [&](int kv0, bf16x8* d) {
        const u16* kr0 = kb + (size_t)(kv0 + lr) * C_DIM;
        const u16* kr1 = kb + (size_t)(kv0 + 16 + lr) * C_DIM;
        d[0] = *(const bf16x8*)(kr0 + lg * 8);
        d[1] = *(const bf16x8*)(kr0 + 32 + lg * 8);
        d[2] = *(const bf16x8*)(kr1 + lg * 8);
        d[3] = *(const bf16x8*)(kr1 + 32 + lg * 8);
    };

    float m = -__builtin_inff(), lsum = 0.f;

    // ---- pass 1: row max + sumexp (exp2 space), K pipelined ----
    loadK(0, kc);
    for (int kv0 = 0; kv0 < kv_end; kv0 += 32) {
        if (kv0 + 32 < kv_end) loadK(kv0 + 32, kn);
        f32x4 s[2] = {};
        s[0] = __builtin_amdgcn_mfma_f32_16x16x32_bf16(kc[0], aq0, s[0], 0, 0, 0);
        s[0] = __builtin_amdgcn_mfma_f32_16x16x32_bf16(kc[1], aq1, s[0], 0, 0, 0);
        s[1] = __builtin_amdgcn_mfma_f32_16x16x32_bf16(kc[2], aq0, s[1], 0, 0, 0);
        s[1] = __builtin_amdgcn_mfma_f32_16x16x32_bf16(kc[3], aq1, s[1], 0, 0, 0);
        float sv[2][4];
        float mt = -__builtin_inff();
#pragma unroll
        for (int t = 0; t < 2; ++t)
#pragma unroll
            for (int r = 0; r < 4; ++r) {
                float v = s[t][r] * SC;
                if (kv0 + 16 * t + 4 * lg + r > qrow) v = -__builtin_inff();
                sv[t][r] = v;
                mt = fmaxf(mt, v);
            }
        mt = fmaxf(mt, __shfl_xor(mt, 16));
        mt = fmaxf(mt, __shfl_xor(mt, 32));
        const float mn = fmaxf(m, mt);
        float e = 0.f;
#pragma unroll
        for (int t = 0; t < 2; ++t)
#pragma unroll
            for (int r = 0; r < 4; ++r) e += fexp2(sv[t][r] - mn);
        e += __shfl_xor(e, 16);
        e += __shfl_xor(e, 32);
        lsum = lsum * fexp2(m - mn) + e;
        m = mn;
#pragma unroll
        for (int i = 0; i < 4; ++i) kc[i] = kn[i];
    }

    const float rl = 1.f / lsum;
    f32x4 cacc[4] = {};

    // ---- pass 2: causal tiles only; write P + accumulate PV ----
    loadK(0, kc);
    for (int kv0 = 0; kv0 < kv_end; kv0 += 32) {
        // V for current tile: issue early so it covers softmax/LDS chain
        bf16x8 vf[4];
#pragma unroll
        for (int dt = 0; dt < 4; ++dt)
            vf[dt] = *(const bf16x8*)(vtb + (size_t)(dt * 16 + lr) * T_SEQ + kv0 + lg * 8);
        if (kv0 + 32 < kv_end) loadK(kv0 + 32, kn);

        f32x4 s[2] = {};
        s[0] = __builtin_amdgcn_mfma_f32_16x16x32_bf16(kc[0], aq0, s[0], 0, 0, 0);
        s[0] = __builtin_amdgcn_mfma_f32_16x16x32_bf16(kc[1], aq1, s[0], 0, 0, 0);
        s[1] = __builtin_amdgcn_mfma_f32_16x16x32_bf16(kc[2], aq0, s[1], 0, 0, 0);
        s[1] = __builtin_amdgcn_mfma_f32_16x16x32_bf16(kc[3], aq1, s[1], 0, 0, 0);

#pragma unroll
        for (int t = 0; t < 2; ++t) {
            float p[4];
#pragma unroll
            for (int r = 0; r < 4; ++r) {
                float v = s[t][r] * SC;
                if (kv0 + 16 * t + 4 * lg + r > qrow) v = -__builtin_inff();
                p[r] = fexp2(v - m) * rl;
            }
            *(float4*)(ab + (size_t)qrow * T_SEQ + kv0 + 16 * t + 4 * lg) =
                make_float4(p[0], p[1], p[2], p[3]);
            union { u16 hh[4]; uint2 q2; } pk;
#pragma unroll
            for (int r = 0; r < 4; ++r) pk.hh[r] = f2bf(p[r]);
            *(uint2*)&plds[lr][16 * t + 4 * lg] = pk.q2;
        }
        asm volatile("s_waitcnt lgkmcnt(0)" ::: "memory");
        const bf16x8 pa = *(const bf16x8*)&plds[lr][lg * 8];
#pragma unroll
        for (int dt = 0; dt < 4; ++dt)
            cacc[dt] = __builtin_amdgcn_mfma_f32_16x16x32_bf16(pa, vf[dt], cacc[dt], 0, 0, 0);
#pragma unroll
        for (int i = 0; i < 4; ++i) kc[i] = kn[i];
    }

    // ---- ctx write ----
    u16* cb = ctx + bh_off;
#pragma unroll
    for (int dt = 0; dt < 4; ++dt)
#pragma unroll
        for (int r = 0; r < 4; ++r)
            cb[(size_t)(q0 + lg * 4 + r) * C_DIM + dt * 16 + lr] = f2bf(cacc[dt][r]);

    // ---- zero-fill upper triangle: tight streaming float4 stores ----
    const int zstart = (kv_end + 31) & ~31;
    const float4 z4 = make_float4(0.f, 0.f, 0.f, 0.f);
    for (int i = 0; i < 16; ++i) {
        float* zr = ab + (size_t)(q0 + i) * T_SEQ;
        for (int c = zstart + l * 4; c < T_SEQ; c += 256)
            *(float4*)(zr + c) = z4;
    }
}

// ---------------------------------------------------------------------------
extern "C" void kernel_launch(void* const* d_in, const int* in_sizes, int n_in,
                              void* d_out, int out_size, void* d_ws, size_t ws_size,
                              hipStream_t stream)
{
    const float* q  = (const float*)d_in[0];
    const float* k  = (const float*)d_in[1];
    const float* Wq = (const float*)d_in[2];
    const float* bq = (const float*)d_in[3];
    const float* Wk = (const float*)d_in[4];
    const float* bk = (const float*)d_in[5];
    const float* Wv = (const float*)d_in[6];
    const float* bv = (const float*)d_in[7];
    const float* Wo = (const float*)d_in[8];
    const float* bo = (const float*)d_in[9];
    (void)in_sizes; (void)n_in; (void)out_size; (void)ws_size;

    float* out = (float*)d_out;
    float* attn = out + (size_t)BATCH * T_SEQ * C_DIM;

    const size_t MC = (size_t)BATCH * T_SEQ * C_DIM;   // 4,194,304 elems
    u16* qp  = (u16*)d_ws;
    u16* kp  = qp + MC;
    u16* vt  = kp + MC;          // V^T: [B][H][D][T]
    u16* ctx = vt + MC;
    u16* WqT = ctx + MC;
    u16* WkT = WqT + (size_t)C_DIM * C_DIM;
    u16* WvT = WkT + (size_t)C_DIM * C_DIM;
    u16* WoT = WvT + (size_t)C_DIM * C_DIM;

    transpose_to_bf16<<<dim3(32, 32, 4), dim3(32, 8), 0, stream>>>(
        Wq, Wk, Wv, Wo, WqT, WkT, WvT, WoT);

    const int M = BATCH * T_SEQ;
    dim3 gg(C_DIM / 128, M / 128);
    gemm_bt<true,  0><<<gg, 256, 0, stream>>>(q,  WqT, bq, qp, M, C_DIM, C_DIM);
    gemm_bt<true,  0><<<gg, 256, 0, stream>>>(k,  WkT, bk, kp, M, C_DIM, C_DIM);
    gemm_bt<false, 2><<<gg, 256, 0, stream>>>(kp, WvT, bv, vt, M, C_DIM, C_DIM);

    attn_kernel<<<dim3(T_SEQ / 16, NH, BATCH), 64, 0, stream>>>(qp, kp, vt, ctx, attn);

    gemm_bt<false, 1><<<gg, 256, 0, stream>>>(ctx, WoT, bo, out, M, C_DIM, C_DIM);
}

// Round 4
// 446.260 us; speedup vs baseline: 1.1837x; 1.1837x over previous
//
#include <hip/hip_runtime.h>

typedef __attribute__((ext_vector_type(8))) short bf16x8;
typedef __attribute__((ext_vector_type(4))) float f32x4;
typedef unsigned short u16;
typedef unsigned int u32;

#define T_SEQ 2048
#define C_DIM 1024
#define NH 16
#define HD 64
#define BATCH 2

__device__ __forceinline__ u16 f2bf(float f) {
    union { float f; u32 u; } v; v.f = f;
    u32 u = v.u;
    u32 r = (u + 0x7FFFu + ((u >> 16) & 1u)) >> 16;
    return (u16)r;
}

__device__ __forceinline__ float fexp2(float x) { return __builtin_amdgcn_exp2f(x); }

// ---------------------------------------------------------------------------
// Transpose 4 weight matrices [C,C] f32 -> [C,C] bf16 (WT[n][k] = W[k][n])
// ---------------------------------------------------------------------------
__global__ __launch_bounds__(256) void transpose_to_bf16(
    const float* __restrict__ W0, const float* __restrict__ W1,
    const float* __restrict__ W2, const float* __restrict__ W3,
    u16* __restrict__ O0, u16* __restrict__ O1,
    u16* __restrict__ O2, u16* __restrict__ O3)
{
    __shared__ float tile[32][33];
    const float* W = blockIdx.z == 0 ? W0 : blockIdx.z == 1 ? W1 : blockIdx.z == 2 ? W2 : W3;
    u16* O = blockIdx.z == 0 ? O0 : blockIdx.z == 1 ? O1 : blockIdx.z == 2 ? O2 : O3;
    const int tx = threadIdx.x, ty = threadIdx.y;
    const int bx = blockIdx.x * 32, by = blockIdx.y * 32;
#pragma unroll
    for (int i = 0; i < 4; ++i)
        tile[ty + i * 8][tx] = W[(size_t)(by + ty + i * 8) * C_DIM + bx + tx];
    __syncthreads();
#pragma unroll
    for (int i = 0; i < 4; ++i)
        O[(size_t)(bx + ty + i * 8) * C_DIM + by + tx] = f2bf(tile[tx][ty + i * 8]);
}

// ---------------------------------------------------------------------------
// GEMM: Y[M,N] = X[M,K] @ W[K,N] + bias, with WT[N,K] (pre-transposed bf16).
// OMODE: 0 = bf16 row-major, 1 = f32 row-major,
//        2 = bf16 transposed per-head: Y[b][h][d][t]  (for V^T)
// ---------------------------------------------------------------------------
template<bool XF32, int OMODE>
__global__ __launch_bounds__(256) void gemm_bt(
    const void* __restrict__ Xv, const u16* __restrict__ WT,
    const float* __restrict__ bias, void* __restrict__ Yv,
    int M, int N, int K)
{
    __shared__ u16 As[128 * 32];
    __shared__ u16 Bs[128 * 32];
    const int tid = threadIdx.x;
    const int w = tid >> 6, l = tid & 63;
    const int lr = l & 15, lg = l >> 4;
    const int m0 = blockIdx.y * 128, n0 = blockIdx.x * 128;
    const int wr = (w >> 1) * 64, wc = (w & 1) * 64;
    f32x4 acc[4][4] = {};

    for (int k0 = 0; k0 < K; k0 += 32) {
        __syncthreads();
#pragma unroll
        for (int r = 0; r < 2; ++r) {
            const int idx = r * 256 + tid;      // 0..511
            const int row = idx >> 2, cg = idx & 3;
            if (XF32) {
                const float* g = (const float*)Xv + (size_t)(m0 + row) * K + k0 + cg * 8;
                float4 a0 = *(const float4*)g;
                float4 a1 = *(const float4*)(g + 4);
                union { u16 h[8]; uint4 q; } pk;
                pk.h[0] = f2bf(a0.x); pk.h[1] = f2bf(a0.y);
                pk.h[2] = f2bf(a0.z); pk.h[3] = f2bf(a0.w);
                pk.h[4] = f2bf(a1.x); pk.h[5] = f2bf(a1.y);
                pk.h[6] = f2bf(a1.z); pk.h[7] = f2bf(a1.w);
                *(uint4*)&As[row * 32 + cg * 8] = pk.q;
            } else {
                const u16* g = (const u16*)Xv + (size_t)(m0 + row) * K + k0 + cg * 8;
                *(uint4*)&As[row * 32 + cg * 8] = *(const uint4*)g;
            }
            const u16* gb = WT + (size_t)(n0 + row) * K + k0 + cg * 8;
            *(uint4*)&Bs[row * 32 + cg * 8] = *(const uint4*)gb;
        }
        __syncthreads();
        bf16x8 af[4], bfr[4];
#pragma unroll
        for (int i = 0; i < 4; ++i)
            af[i] = *(const bf16x8*)&As[(wr + i * 16 + lr) * 32 + lg * 8];
#pragma unroll
        for (int j = 0; j < 4; ++j)
            bfr[j] = *(const bf16x8*)&Bs[(wc + j * 16 + lr) * 32 + lg * 8];
#pragma unroll
        for (int i = 0; i < 4; ++i)
#pragma unroll
            for (int j = 0; j < 4; ++j)
                acc[i][j] = __builtin_amdgcn_mfma_f32_16x16x32_bf16(af[i], bfr[j], acc[i][j], 0, 0, 0);
    }

#pragma unroll
    for (int i = 0; i < 4; ++i) {
        const int rowb = m0 + wr + i * 16 + lg * 4;
#pragma unroll
        for (int j = 0; j < 4; ++j) {
            const int col = n0 + wc + j * 16 + lr;
            const float bv = bias[col];
            if (OMODE == 2) {
                union { u16 h[4]; uint2 q; } pk;
#pragma unroll
                for (int r = 0; r < 4; ++r) pk.h[r] = f2bf(acc[i][j][r] + bv);
                const int bb = rowb >> 11, tt = rowb & 2047;
                const int hh = col >> 6, dd = col & 63;
                u16* dst = (u16*)Yv + ((size_t)((bb * NH + hh) * HD + dd)) * T_SEQ + tt;
                *(uint2*)dst = pk.q;
            } else {
#pragma unroll
                for (int r = 0; r < 4; ++r) {
                    const float v = acc[i][j][r] + bv;
                    if (OMODE == 1)
                        ((float*)Yv)[(size_t)(rowb + r) * N + col] = v;
                    else
                        ((u16*)Yv)[(size_t)(rowb + r) * N + col] = f2bf(v);
                }
            }
        }
    }
}

// ---------------------------------------------------------------------------
// Causal attention. Block = (b, h, 16 q-rows), 8 waves (512 thr) SPLIT THE KV
// RANGE round-robin (tile = 32 kv). Phase A: per-wave in-lane partial (m,l),
// combined via LDS. Phase B: recompute S, write normalized P, partial PV per
// wave, PV reduced via padded LDS. Masked elements use -1e30 sentinel so
// fully-masked lanes/waves vanish with weight exp2(-1e30 - m) = 0.
// ---------------------------------------------------------------------------
#define PV_QS 67            // float stride per q-row in pvbuf
#define PV_WS (16 * PV_QS + 8)  // float stride per wave block (1080)

__global__ __launch_bounds__(512) void attn_kernel(
    const u16* __restrict__ qp, const u16* __restrict__ kp,
    const u16* __restrict__ vt, u16* __restrict__ ctx,
    float* __restrict__ attn)
{
    __shared__ u16 plds[8][16][40];          // per-wave P tile   (10.2 KB)
    __shared__ float statm[8][16], statl[8][16];
    __shared__ float pvbuf[8 * PV_WS];       // PV partials       (34.6 KB)

    const int tid = threadIdx.x;
    const int w = tid >> 6, l = tid & 63;
    const int lr = l & 15, lg = l >> 4;
    const int b = blockIdx.z, h = blockIdx.y;
    const int strip = (gridDim.x - 1) - blockIdx.x;   // heavy-first
    const int q0 = strip * 16;

    const size_t bh_off = (size_t)b * T_SEQ * C_DIM + h * HD;
    const u16* qb = qp + bh_off;
    const u16* kb = kp + bh_off;
    const u16* vtb = vt + ((size_t)(b * NH + h) * HD) * T_SEQ;
    float* ab = attn + (size_t)(b * NH + h) * T_SEQ * T_SEQ;

    const float SC = 0.125f * 1.44269504088896f;   // 1/sqrt(64) * log2(e)
    const float MNEG = -1e30f;

    const bf16x8 aq0 = *(const bf16x8*)(qb + (size_t)(q0 + lr) * C_DIM + lg * 8);
    const bf16x8 aq1 = *(const bf16x8*)(qb + (size_t)(q0 + lr) * C_DIM + 32 + lg * 8);

    const int qrow = q0 + lr;
    const int kv_end = q0 + 16;
    const int n_tiles = (kv_end + 31) >> 5;

    // ---- phase A: per-wave partial (m, l), fully in-lane per tile ----
    float ml = MNEG, ll = 0.f;
    for (int ti = w; ti < n_tiles; ti += 8) {
        const int kv0 = ti * 32;
        const u16* kr0 = kb + (size_t)(kv0 + lr) * C_DIM;
        const u16* kr1 = kb + (size_t)(kv0 + 16 + lr) * C_DIM;
        bf16x8 k0 = *(const bf16x8*)(kr0 + lg * 8);
        bf16x8 k1 = *(const bf16x8*)(kr0 + 32 + lg * 8);
        bf16x8 k2 = *(const bf16x8*)(kr1 + lg * 8);
        bf16x8 k3 = *(const bf16x8*)(kr1 + 32 + lg * 8);
        f32x4 s[2] = {};
        s[0] = __builtin_amdgcn_mfma_f32_16x16x32_bf16(k0, aq0, s[0], 0, 0, 0);
        s[0] = __builtin_amdgcn_mfma_f32_16x16x32_bf16(k1, aq1, s[0], 0, 0, 0);
        s[1] = __builtin_amdgcn_mfma_f32_16x16x32_bf16(k2, aq0, s[1], 0, 0, 0);
        s[1] = __builtin_amdgcn_mfma_f32_16x16x32_bf16(k3, aq1, s[1], 0, 0, 0);
        float sv[8];
        float mt = MNEG;
#pragma unroll
        for (int t = 0; t < 2; ++t)
#pragma unroll
            for (int r = 0; r < 4; ++r) {
                float v = s[t][r] * SC;
                if (kv0 + 16 * t + 4 * lg + r > qrow) v = MNEG;
                sv[t * 4 + r] = v;
                mt = fmaxf(mt, v);
            }
        const float mn = fmaxf(ml, mt);
        float e = 0.f;
#pragma unroll
        for (int i = 0; i < 8; ++i) e += fexp2(sv[i] - mn);
        ll = ll * fexp2(ml - mn) + e;
        ml = mn;
    }
    // cross-lane (lg) combine: xor 16, 32
#pragma unroll
    for (int d = 16; d <= 32; d <<= 1) {
        const float mo = __shfl_xor(ml, d);
        const float lo = __shfl_xor(ll, d);
        const float mn = fmaxf(ml, mo);
        ll = ll * fexp2(ml - mn) + lo * fexp2(mo - mn);
        ml = mn;
    }
    if (l < 16) { statm[w][lr] = ml; statl[w][lr] = ll; }
    __syncthreads();

    float mf = MNEG;
#pragma unroll
    for (int ww = 0; ww < 8; ++ww) mf = fmaxf(mf, statm[ww][lr]);
    float lf = 0.f;
#pragma unroll
    for (int ww = 0; ww < 8; ++ww) lf += statl[ww][lr] * fexp2(statm[ww][lr] - mf);
    const float rl = 1.f / lf;

    // ---- phase B: write normalized P + partial PV per wave ----
    f32x4 cacc[4] = {};
    for (int ti = w; ti < n_tiles; ti += 8) {
        const int kv0 = ti * 32;
        bf16x8 vf[4];
#pragma unroll
        for (int dt = 0; dt < 4; ++dt)
            vf[dt] = *(const bf16x8*)(vtb + (size_t)(dt * 16 + lr) * T_SEQ + kv0 + lg * 8);
        const u16* kr0 = kb + (size_t)(kv0 + lr) * C_DIM;
        const u16* kr1 = kb + (size_t)(kv0 + 16 + lr) * C_DIM;
        bf16x8 k0 = *(const bf16x8*)(kr0 + lg * 8);
        bf16x8 k1 = *(const bf16x8*)(kr0 + 32 + lg * 8);
        bf16x8 k2 = *(const bf16x8*)(kr1 + lg * 8);
        bf16x8 k3 = *(const bf16x8*)(kr1 + 32 + lg * 8);
        f32x4 s[2] = {};
        s[0] = __builtin_amdgcn_mfma_f32_16x16x32_bf16(k0, aq0, s[0], 0, 0, 0);
        s[0] = __builtin_amdgcn_mfma_f32_16x16x32_bf16(k1, aq1, s[0], 0, 0, 0);
        s[1] = __builtin_amdgcn_mfma_f32_16x16x32_bf16(k2, aq0, s[1], 0, 0, 0);
        s[1] = __builtin_amdgcn_mfma_f32_16x16x32_bf16(k3, aq1, s[1], 0, 0, 0);
#pragma unroll
        for (int t = 0; t < 2; ++t) {
            float p[4];
#pragma unroll
            for (int r = 0; r < 4; ++r) {
                float v = s[t][r] * SC;
                if (kv0 + 16 * t + 4 * lg + r > qrow) v = MNEG;
                p[r] = fexp2(v - mf) * rl;
            }
            *(float4*)(ab + (size_t)qrow * T_SEQ + kv0 + 16 * t + 4 * lg) =
                make_float4(p[0], p[1], p[2], p[3]);
            union { u16 hh[4]; uint2 q2; } pk;
#pragma unroll
            for (int r = 0; r < 4; ++r) pk.hh[r] = f2bf(p[r]);
            *(uint2*)&plds[w][lr][16 * t + 4 * lg] = pk.q2;
        }
        asm volatile("s_waitcnt lgkmcnt(0)" ::: "memory");
        const bf16x8 pa = *(const bf16x8*)&plds[w][lr][lg * 8];
#pragma unroll
        for (int dt = 0; dt < 4; ++dt)
            cacc[dt] = __builtin_amdgcn_mfma_f32_16x16x32_bf16(pa, vf[dt], cacc[dt], 0, 0, 0);
    }

    // dump PV partials (cacc[dt][r] = ctx[q = 4*lg + r][d = dt*16 + lr])
    {
        float* pw = pvbuf + w * PV_WS;
#pragma unroll
        for (int dt = 0; dt < 4; ++dt)
#pragma unroll
            for (int r = 0; r < 4; ++r)
                pw[(4 * lg + r) * PV_QS + dt * 16 + lr] = cacc[dt][r];
    }
    __syncthreads();

    // reduce PV across waves + write ctx (bf16): 1024 elems, 512 thr x 2
    {
        const int qq = tid >> 5;            // 0..15
        const int d0 = (tid & 31) * 2;      // 0..62
        float s0 = 0.f, s1 = 0.f;
#pragma unroll
        for (int ww = 0; ww < 8; ++ww) {
            const float* pw = pvbuf + ww * PV_WS + qq * PV_QS;
            s0 += pw[d0];
            s1 += pw[d0 + 1];
        }
        union { u16 hh[2]; u32 u; } pk;
        pk.hh[0] = f2bf(s0); pk.hh[1] = f2bf(s1);
        u16* cb = ctx + bh_off;
        *(u32*)(cb + (size_t)(q0 + qq) * C_DIM + d0) = pk.u;
    }

    // zero-fill upper region [n_tiles*32, T) for all 16 rows, whole block
    {
        const int zs = n_tiles * 32;
        const int row = tid >> 5;           // 0..15
        const int c0 = (tid & 31) * 4;
        float* zr = ab + (size_t)(q0 + row) * T_SEQ;
        const float4 z4 = make_float4(0.f, 0.f, 0.f, 0.f);
        for (int c = zs + c0; c < T_SEQ; c += 128)
            *(float4*)(zr + c) = z4;
    }
}

// ---------------------------------------------------------------------------
extern "C" void kernel_launch(void* const* d_in, const int* in_sizes, int n_in,
                              void* d_out, int out_size, void* d_ws, size_t ws_size,
                              hipStream_t stream)
{
    const float* q  = (const float*)d_in[0];
    const float* k  = (const float*)d_in[1];
    const float* Wq = (const float*)d_in[2];
    const float* bq = (const float*)d_in[3];
    const float* Wk = (const float*)d_in[4];
    const float* bk = (const float*)d_in[5];
    const float* Wv = (const float*)d_in[6];
    const float* bv = (const float*)d_in[7];
    const float* Wo = (const float*)d_in[8];
    const float* bo = (const float*)d_in[9];
    (void)in_sizes; (void)n_in; (void)out_size; (void)ws_size;

    float* out = (float*)d_out;
    float* attn = out + (size_t)BATCH * T_SEQ * C_DIM;

    const size_t MC = (size_t)BATCH * T_SEQ * C_DIM;   // 4,194,304 elems
    u16* qp  = (u16*)d_ws;
    u16* kp  = qp + MC;
    u16* vt  = kp + MC;          // V^T: [B][H][D][T]
    u16* ctx = vt + MC;
    u16* WqT = ctx + MC;
    u16* WkT = WqT + (size_t)C_DIM * C_DIM;
    u16* WvT = WkT + (size_t)C_DIM * C_DIM;
    u16* WoT = WvT + (size_t)C_DIM * C_DIM;

    transpose_to_bf16<<<dim3(32, 32, 4), dim3(32, 8), 0, stream>>>(
        Wq, Wk, Wv, Wo, WqT, WkT, WvT, WoT);

    const int M = BATCH * T_SEQ;
    dim3 gg(C_DIM / 128, M / 128);
    gemm_bt<true,  0><<<gg, 256, 0, stream>>>(q,  WqT, bq, qp, M, C_DIM, C_DIM);
    gemm_bt<true,  0><<<gg, 256, 0, stream>>>(k,  WkT, bk, kp, M, C_DIM, C_DIM);
    gemm_bt<false, 2><<<gg, 256, 0, stream>>>(kp, WvT, bv, vt, M, C_DIM, C_DIM);

    attn_kernel<<<dim3(T_SEQ / 16, NH, BATCH), 512, 0, stream>>>(qp, kp, vt, ctx, attn);

    gemm_bt<false, 1><<<gg, 256, 0, stream>>>(ctx, WoT, bo, out, M, C_DIM, C_DIM);
}